// Round 1
// baseline (15967.552 us; speedup 1.0000x reference)
//
#include <hip/hip_runtime.h>
#include <hip/hip_bf16.h>

#define N_NODES   50000
#define N_EDGES   500000
#define D_MODEL   128
#define NHEAD     8
#define D_HEAD    16
#define NUM_KEYS  8
#define NUM_ETYPES 4
#define NUM_STRINGS 20000
#define NUM_BLOCKS 2
#define N_TARGETS 128

typedef unsigned short u16;
typedef unsigned int   u32;

// ---------- bf16 helpers ----------
__device__ __forceinline__ float bflo(u32 u)  { return __uint_as_float(u << 16); }
__device__ __forceinline__ float bfhi(u32 u)  { return __uint_as_float(u & 0xffff0000u); }
__device__ __forceinline__ float bf2f(u16 u)  { return __uint_as_float(((u32)u) << 16); }
__device__ __forceinline__ u16   f2bf(float f){
  u32 u = __float_as_uint(f);
  u += 0x7fffu + ((u >> 16) & 1u);   // round-to-nearest-even
  return (u16)(u >> 16);
}
// monotone f32 <-> u32 mapping for atomicMax-based segment max
__device__ __forceinline__ u32 enc_f(float f){
  u32 u = __float_as_uint(f);
  return (u & 0x80000000u) ? ~u : (u | 0x80000000u);
}
__device__ __forceinline__ float dec_f(u32 u){
  return (u & 0x80000000u) ? __uint_as_float(u ^ 0x80000000u) : __uint_as_float(~u);
}

// ---------- dtype detector: 1 = inputs are bf16, 0 = inputs are f32 ----------
__global__ void detect_dtype(const u16* raw, int* flag){
  __shared__ int cnt;
  if (threadIdx.x == 0) cnt = 0;
  __syncthreads();
  int sane = 0;
  #pragma unroll
  for (int k = 0; k < 4; k++){
    u16 u = raw[threadIdx.x * 4 + k];
    int e = (u >> 7) & 0xff;           // bf16 exponent field
    if (e >= 100 && e <= 145) sane++;  // |x| roughly in [2^-27, 2^18]
  }
  atomicAdd(&cnt, sane);
  __syncthreads();
  if (threadIdx.x == 0) *flag = (cnt >= 870) ? 1 : 0;  // 85% of 1024
}

// ---------- convert a float input (bf16 or f32) to f32 workspace copy ----------
__global__ void cvt_kernel(const void* src, float* dst, int n, const int* flag){
  int i = blockIdx.x * 256 + threadIdx.x;
  if (i >= n) return;
  dst[i] = (*flag) ? bf2f(((const u16*)src)[i]) : ((const float*)src)[i];
}

// ---------- feat[n,d] = emb[value_ids[n], d] ----------
__global__ void gather_feat(const void* emb_raw, const int* __restrict__ vid,
                            const int* __restrict__ flag, float* __restrict__ feat){
  int i = blockIdx.x * 256 + threadIdx.x;          // N_NODES*128 exact
  int n = i >> 7, d = i & 127;
  int e = (vid[n] << 7) + d;
  feat[i] = (*flag) ? bf2f(((const u16*)emb_raw)[e]) : ((const float*)emb_raw)[e];
}

// ---------- per-node projections: q (own key), k_all & v_all (all 4 etypes) ----------
__global__ __launch_bounds__(128) void proj_qkv(
    const float* __restrict__ feat,
    const float* __restrict__ qwf,   // [2,8,128,128]
    const float* __restrict__ kwf,   // [2,4,128,128]
    const float* __restrict__ vwf,   // [2,4,128,128]
    const int* __restrict__ key_ids,
    u16* __restrict__ q_bf,          // [N,128]
    u16* __restrict__ k_bf,          // [N,4,128]
    u16* __restrict__ v_bf,          // [N,4,128]
    int blk)
{
  __shared__ float sf[128];
  int n = blockIdx.x, t = threadIdx.x;
  sf[t] = feat[(n << 7) + t];
  __syncthreads();
  int key = key_ids[n];
  {
    const float4* wr = (const float4*)(qwf + (size_t)(((blk * 8 + key) << 7) + t) * 128);
    float acc = 0.f;
    #pragma unroll
    for (int j = 0; j < 32; j++){
      float4 w = wr[j];
      acc = fmaf(w.x, sf[4*j+0], acc); acc = fmaf(w.y, sf[4*j+1], acc);
      acc = fmaf(w.z, sf[4*j+2], acc); acc = fmaf(w.w, sf[4*j+3], acc);
    }
    q_bf[(n << 7) + t] = f2bf(acc);
  }
  #pragma unroll
  for (int te = 0; te < 4; te++){
    const float4* wr = (const float4*)(kwf + (size_t)(((blk * 4 + te) << 7) + t) * 128);
    float acc = 0.f;
    #pragma unroll
    for (int j = 0; j < 32; j++){
      float4 w = wr[j];
      acc = fmaf(w.x, sf[4*j+0], acc); acc = fmaf(w.y, sf[4*j+1], acc);
      acc = fmaf(w.z, sf[4*j+2], acc); acc = fmaf(w.w, sf[4*j+3], acc);
    }
    k_bf[(n << 9) + (te << 7) + t] = f2bf(acc);
  }
  #pragma unroll
  for (int te = 0; te < 4; te++){
    const float4* wr = (const float4*)(vwf + (size_t)(((blk * 4 + te) << 7) + t) * 128);
    float acc = 0.f;
    #pragma unroll
    for (int j = 0; j < 32; j++){
      float4 w = wr[j];
      acc = fmaf(w.x, sf[4*j+0], acc); acc = fmaf(w.y, sf[4*j+1], acc);
      acc = fmaf(w.z, sf[4*j+2], acc); acc = fmaf(w.w, sf[4*j+3], acc);
    }
    v_bf[(n << 9) + (te << 7) + t] = f2bf(acc);
  }
}

__device__ __forceinline__ float dot8(uint4 a, uint4 b){
  return bflo(a.x)*bflo(b.x) + bfhi(a.x)*bfhi(b.x)
       + bflo(a.y)*bflo(b.y) + bfhi(a.y)*bfhi(b.y)
       + bflo(a.z)*bflo(b.z) + bfhi(a.z)*bfhi(b.z)
       + bflo(a.w)*bflo(b.w) + bfhi(a.w)*bfhi(b.w);
}

// ---------- scores[e,h] = (q[dst] . k_e) * 0.25 ; segment max via atomicMax ----------
__global__ void edge_scores(const u16* __restrict__ q, const u16* __restrict__ k,
                            const int* __restrict__ src, const int* __restrict__ dst,
                            const int* __restrict__ et,
                            float* __restrict__ scores, u32* __restrict__ menc){
  int tid = blockIdx.x * 256 + threadIdx.x;
  if (tid >= N_EDGES * 8) return;
  int e = tid >> 3, h = tid & 7;
  int s = src[e], d = dst[e], t = et[e];
  const u16* qp = q + (d << 7) + (h << 4);
  const u16* kp = k + (((s << 2) + t) << 7) + (h << 4);
  uint4 qa = *(const uint4*)qp, qb = *(const uint4*)(qp + 8);
  uint4 ka = *(const uint4*)kp, kb = *(const uint4*)(kp + 8);
  float val = (dot8(qa, ka) + dot8(qb, kb)) * 0.25f;
  scores[tid] = val;
  atomicMax(menc + (d << 3) + h, enc_f(val));
}

// ---------- e = exp(s - m); z = segment sum ----------
__global__ void edge_exp(float* __restrict__ scores, const u32* __restrict__ menc,
                         const int* __restrict__ dst, float* __restrict__ zsum){
  int tid = blockIdx.x * 256 + threadIdx.x;
  if (tid >= N_EDGES * 8) return;
  int e = tid >> 3, h = tid & 7;
  int d = dst[e];
  float m = dec_f(menc[(d << 3) + h]);
  float ex = __expf(scores[tid] - m);
  scores[tid] = ex;
  unsafeAtomicAdd(zsum + (d << 3) + h, ex);
}

// ---------- agg[dst,h,f] += attn * v_e[h,f] ----------
__global__ void edge_agg(const float* __restrict__ scores, const float* __restrict__ zsum,
                         const u16* __restrict__ v,
                         const int* __restrict__ src, const int* __restrict__ dst,
                         const int* __restrict__ et, float* __restrict__ agg){
  int tid = blockIdx.x * 256 + threadIdx.x;
  if (tid >= N_EDGES * 8) return;
  int e = tid >> 3, h = tid & 7;
  int s = src[e], d = dst[e], t = et[e];
  float attn = scores[tid] / (zsum[(d << 3) + h] + 1e-9f);
  const u16* vp = v + (((s << 2) + t) << 7) + (h << 4);
  uint4 va = *(const uint4*)vp, vb = *(const uint4*)(vp + 8);
  float* ap = agg + (d << 7) + (h << 4);
  unsafeAtomicAdd(ap + 0,  attn * bflo(va.x));
  unsafeAtomicAdd(ap + 1,  attn * bfhi(va.x));
  unsafeAtomicAdd(ap + 2,  attn * bflo(va.y));
  unsafeAtomicAdd(ap + 3,  attn * bfhi(va.y));
  unsafeAtomicAdd(ap + 4,  attn * bflo(va.z));
  unsafeAtomicAdd(ap + 5,  attn * bfhi(va.z));
  unsafeAtomicAdd(ap + 6,  attn * bflo(va.w));
  unsafeAtomicAdd(ap + 7,  attn * bfhi(va.w));
  unsafeAtomicAdd(ap + 8,  attn * bflo(vb.x));
  unsafeAtomicAdd(ap + 9,  attn * bfhi(vb.x));
  unsafeAtomicAdd(ap + 10, attn * bflo(vb.y));
  unsafeAtomicAdd(ap + 11, attn * bfhi(vb.y));
  unsafeAtomicAdd(ap + 12, attn * bflo(vb.z));
  unsafeAtomicAdd(ap + 13, attn * bfhi(vb.z));
  unsafeAtomicAdd(ap + 14, attn * bflo(vb.w));
  unsafeAtomicAdd(ap + 15, attn * bfhi(vb.w));
}

// ---------- node proj (own key) + relu + layernorm + residual ----------
__global__ __launch_bounds__(128) void node_update(
    const float* __restrict__ agg, const float* __restrict__ nwf,
    const int* __restrict__ key_ids, const float* __restrict__ gbf,
    float* __restrict__ feat, int blk)
{
  __shared__ float sa[128];
  __shared__ float red[4];
  int n = blockIdx.x, t = threadIdx.x;
  sa[t] = agg[(n << 7) + t];
  __syncthreads();
  int key = key_ids[n];
  const float4* wr = (const float4*)(nwf + (size_t)(((blk * 8 + key) << 7) + t) * 128);
  float acc = 0.f;
  #pragma unroll
  for (int j = 0; j < 32; j++){
    float4 w = wr[j];
    acc = fmaf(w.x, sa[4*j+0], acc); acc = fmaf(w.y, sa[4*j+1], acc);
    acc = fmaf(w.z, sa[4*j+2], acc); acc = fmaf(w.w, sa[4*j+3], acc);
  }
  acc = fmaxf(acc, 0.f);   // relu
  // block-wide mean / mean-of-squares over 128 lanes (2 waves)
  float v1 = acc, v2 = acc * acc;
  #pragma unroll
  for (int o = 32; o > 0; o >>= 1){
    v1 += __shfl_down(v1, o, 64);
    v2 += __shfl_down(v2, o, 64);
  }
  if ((t & 63) == 0){ int w = t >> 6; red[w] = v1; red[2 + w] = v2; }
  __syncthreads();
  float mu  = (red[0] + red[1]) * (1.f / 128.f);
  float ex2 = (red[2] + red[3]) * (1.f / 128.f);
  float var = ex2 - mu * mu;
  float y = (acc - mu) * rsqrtf(var + 1e-5f) * gbf[(blk << 7) + t] + gbf[256 + (blk << 7) + t];
  feat[(n << 7) + t] = y + feat[(n << 7) + t];   // block residual
}

// ---------- target readout; accumulate mean of 2 blocks; dtype-flexible output ----------
__global__ __launch_bounds__(128) void readout(
    const float* __restrict__ feat, const float* __restrict__ twf,
    const int* __restrict__ key_ids, const int* __restrict__ tgt,
    float* __restrict__ outacc, void* dout, const int* __restrict__ flag, int blk)
{
  int t = threadIdx.x;
  int n = tgt[t];
  int key = key_ids[n];
  const float* fr = feat + (n << 7);
  const float* wr = twf + (size_t)((blk * 8 + key) << 7);
  float acc = 0.f;
  #pragma unroll
  for (int d = 0; d < 128; d++) acc = fmaf(fr[d], wr[d], acc);
  if (blk == 0){
    outacc[t] = 0.5f * acc;
  } else {
    float r = outacc[t] + 0.5f * acc;
    if (*flag) ((u16*)dout)[t] = f2bf(r);
    else       ((float*)dout)[t] = r;
  }
}

extern "C" void kernel_launch(void* const* d_in, const int* in_sizes, int n_in,
                              void* d_out, int out_size, void* d_ws, size_t ws_size,
                              hipStream_t stream)
{
  const void* emb = d_in[0];
  const void* qw  = d_in[1];
  const void* kw  = d_in[2];
  const void* vw  = d_in[3];
  const void* nw  = d_in[4];
  const void* tw  = d_in[5];
  const void* lg  = d_in[6];
  const void* lb  = d_in[7];
  const int* value_ids = (const int*)d_in[8];
  const int* key_ids   = (const int*)d_in[9];
  const int* srcp  = (const int*)d_in[10];
  const int* dstp  = (const int*)d_in[11];
  const int* etp   = (const int*)d_in[12];
  const int* tgt   = (const int*)d_in[13];

  char* p = (char*)d_ws;
  auto carve = [&](size_t bytes)->char*{
    char* r = p; p += (bytes + 255) & ~(size_t)255; return r;
  };
  int*    flag  = (int*)   carve(4);
  float*  feat  = (float*) carve((size_t)N_NODES * 128 * 4);
  float*  qwf   = (float*) carve((size_t)2 * 8 * 128 * 128 * 4);
  float*  kwf   = (float*) carve((size_t)2 * 4 * 128 * 128 * 4);
  float*  vwf   = (float*) carve((size_t)2 * 4 * 128 * 128 * 4);
  float*  nwf   = (float*) carve((size_t)2 * 8 * 128 * 128 * 4);
  float*  twf   = (float*) carve((size_t)2 * 8 * 128 * 4);
  float*  gbf   = (float*) carve((size_t)512 * 4);
  u16*    qbf   = (u16*)   carve((size_t)N_NODES * 128 * 2);
  u16*    kbf   = (u16*)   carve((size_t)N_NODES * 512 * 2);
  u16*    vbf   = (u16*)   carve((size_t)N_NODES * 512 * 2);
  float*  scores= (float*) carve((size_t)N_EDGES * 8 * 4);
  u32*    menc  = (u32*)   carve((size_t)N_NODES * 8 * 4);   // contiguous with zsum, agg
  float*  zsum  = (float*) carve((size_t)N_NODES * 8 * 4);
  float*  agg   = (float*) carve((size_t)N_NODES * 128 * 4);
  float*  outacc= (float*) carve((size_t)N_TARGETS * 4);
  (void)outacc; (void)ws_size; (void)n_in; (void)in_sizes; (void)out_size;

  const size_t zero_bytes = (size_t)N_NODES * (8 + 8 + 128) * 4;  // menc+zsum+agg

  detect_dtype<<<1, 256, 0, stream>>>((const u16*)emb, flag);

  auto cvt = [&](const void* s, float* d, int n){
    cvt_kernel<<<(n + 255) / 256, 256, 0, stream>>>(s, d, n, flag);
  };
  cvt(qw, qwf, 2 * 8 * 128 * 128);
  cvt(kw, kwf, 2 * 4 * 128 * 128);
  cvt(vw, vwf, 2 * 4 * 128 * 128);
  cvt(nw, nwf, 2 * 8 * 128 * 128);
  cvt(tw, twf, 2 * 8 * 128);
  cvt(lg, gbf, 256);
  cvt(lb, gbf + 256, 256);

  gather_feat<<<(N_NODES * 128) / 256, 256, 0, stream>>>(emb, value_ids, flag, feat);

  const int egrid = (N_EDGES * 8 + 255) / 256;
  for (int b = 0; b < NUM_BLOCKS; b++){
    hipMemsetAsync(menc, 0, zero_bytes, stream);
    proj_qkv<<<N_NODES, 128, 0, stream>>>(feat, qwf, kwf, vwf, key_ids, qbf, kbf, vbf, b);
    edge_scores<<<egrid, 256, 0, stream>>>(qbf, kbf, srcp, dstp, etp, scores, menc);
    edge_exp<<<egrid, 256, 0, stream>>>(scores, menc, dstp, zsum);
    edge_agg<<<egrid, 256, 0, stream>>>(scores, zsum, vbf, srcp, dstp, etp, agg);
    node_update<<<N_NODES, 128, 0, stream>>>(agg, nwf, key_ids, gbf, feat, b);
    readout<<<1, 128, 0, stream>>>(feat, twf, key_ids, tgt, outacc, d_out, flag, b);
  }
}

// Round 2
// 773.968 us; speedup vs baseline: 20.6308x; 20.6308x over previous
//
#include <hip/hip_runtime.h>
#include <hip/hip_bf16.h>

#define N_NODES   50000
#define N_EDGES   500000
#define D_MODEL   128
#define NHEAD     8
#define D_HEAD    16
#define NUM_KEYS  8
#define NUM_ETYPES 4
#define NUM_BLOCKS 2
#define N_TARGETS 128

typedef unsigned short u16;
typedef unsigned int   u32;
typedef __attribute__((ext_vector_type(8))) short short8;
typedef __attribute__((ext_vector_type(4))) float floatx4;

// ---------- bf16 helpers ----------
__device__ __forceinline__ float bflo(u32 u)  { return __uint_as_float(u << 16); }
__device__ __forceinline__ float bfhi(u32 u)  { return __uint_as_float(u & 0xffff0000u); }
__device__ __forceinline__ float bf2f(u16 u)  { return __uint_as_float(((u32)u) << 16); }
__device__ __forceinline__ u16   f2bf(float f){
  u32 u = __float_as_uint(f);
  u += 0x7fffu + ((u >> 16) & 1u);   // round-to-nearest-even
  return (u16)(u >> 16);
}

// ---------- dtype detector: 1 = inputs are bf16, 0 = inputs are f32 ----------
__global__ void detect_dtype(const u16* raw, int* flag){
  __shared__ int cnt;
  if (threadIdx.x == 0) cnt = 0;
  __syncthreads();
  int sane = 0;
  #pragma unroll
  for (int k = 0; k < 4; k++){
    u16 u = raw[threadIdx.x * 4 + k];
    int e = (u >> 7) & 0xff;
    if (e >= 100 && e <= 145) sane++;
  }
  atomicAdd(&cnt, sane);
  __syncthreads();
  if (threadIdx.x == 0) *flag = (cnt >= 870) ? 1 : 0;
}

// ---------- convert float input (bf16-or-f32) to f32 ----------
__global__ void cvt_f32(const void* src, float* dst, int n, const int* flag){
  int i = blockIdx.x * 256 + threadIdx.x;
  if (i >= n) return;
  dst[i] = (*flag) ? bf2f(((const u16*)src)[i]) : ((const float*)src)[i];
}
// ---------- convert float input (bf16-or-f32) to bf16, with src element offset ----------
__global__ void cvt_bf(const void* src, size_t soff, u16* dst, int n, const int* flag){
  int i = blockIdx.x * 256 + threadIdx.x;
  if (i >= n) return;
  dst[i] = (*flag) ? ((const u16*)src)[soff + i] : f2bf(((const float*)src)[soff + i]);
}

// ---------- feat gather: f32 + bf16 copies ----------
__global__ void gather_feat(const void* emb_raw, const int* __restrict__ vid,
                            const int* __restrict__ flag,
                            float* __restrict__ feat, u16* __restrict__ featbf){
  int i = blockIdx.x * 256 + threadIdx.x;          // N_NODES*128 exact
  int n = i >> 7, d = i & 127;
  int e = (vid[n] << 7) + d;
  float v = (*flag) ? bf2f(((const u16*)emb_raw)[e]) : ((const float*)emb_raw)[e];
  feat[i] = v;
  featbf[i] = f2bf(v);
}

// ---------- CSR build ----------
__global__ void hist_dst(const int* __restrict__ dst, int* __restrict__ deg){
  int e = blockIdx.x * 256 + threadIdx.x;
  if (e < N_EDGES) atomicAdd(&deg[dst[e]], 1);
}
__global__ __launch_bounds__(1024) void scan_deg(const int* __restrict__ deg,
                                                 int* __restrict__ rs, int* __restrict__ cur){
  __shared__ int s[1024];
  int t = threadIdx.x;
  int lo = t * 49, hi = min(lo + 49, N_NODES);
  int sum = 0;
  for (int i = lo; i < hi; i++) sum += deg[i];
  s[t] = sum;
  __syncthreads();
  for (int off = 1; off < 1024; off <<= 1){
    int v = (t >= off) ? s[t - off] : 0;
    __syncthreads();
    s[t] += v;
    __syncthreads();
  }
  int run = s[t] - sum;   // exclusive base for this chunk
  for (int i = lo; i < hi; i++){
    rs[i] = run; cur[i] = run;
    run += deg[i];
  }
}
__global__ void scatter_edges(const int* __restrict__ src, const int* __restrict__ dst,
                              const int* __restrict__ et, int* __restrict__ cur,
                              u32* __restrict__ epk){
  int e = blockIdx.x * 256 + threadIdx.x;
  if (e >= N_EDGES) return;
  int pos = atomicAdd(&cur[dst[e]], 1);
  epk[pos] = ((u32)src[e] << 2) | (u32)et[e];
}

// ---------- MFMA GEMM: C[M,Ncols] = A[M,128] * Bt[Ncols,128]^T, all bf16, f32 accum ----------
__global__ __launch_bounds__(256) void gemm_bt(
    const u16* __restrict__ A, const u16* __restrict__ Bt,
    u16* __restrict__ C, int Mreal, int Ncols)
{
  int m0 = blockIdx.x * 128, n0 = blockIdx.y * 128;
  int w = threadIdx.x >> 6, l = threadIdx.x & 63;
  int wm = m0 + (w & 1) * 64, wn = n0 + (w >> 1) * 64;
  int lr = l & 15, lk = (l >> 4) * 8;
  floatx4 acc[4][4] = {};
  #pragma unroll
  for (int kk = 0; kk < 4; kk++){
    int kbase = kk * 32 + lk;
    short8 af[4], bfr[4];
    #pragma unroll
    for (int i = 0; i < 4; i++){
      int row = wm + i * 16 + lr; row = row < Mreal ? row : Mreal - 1;
      af[i] = *(const short8*)(A + (size_t)row * 128 + kbase);
    }
    #pragma unroll
    for (int j = 0; j < 4; j++){
      int col = wn + j * 16 + lr;
      bfr[j] = *(const short8*)(Bt + (size_t)col * 128 + kbase);
    }
    #pragma unroll
    for (int i = 0; i < 4; i++)
      #pragma unroll
      for (int j = 0; j < 4; j++)
        acc[i][j] = __builtin_amdgcn_mfma_f32_16x16x32_bf16(af[i], bfr[j], acc[i][j], 0, 0, 0);
  }
  #pragma unroll
  for (int i = 0; i < 4; i++){
    #pragma unroll
    for (int r = 0; r < 4; r++){
      int row = wm + i * 16 + (l >> 4) * 4 + r;
      if (row >= Mreal) continue;
      #pragma unroll
      for (int j = 0; j < 4; j++){
        int col = wn + j * 16 + (l & 15);
        C[(size_t)row * Ncols + col] = f2bf(acc[i][j][r]);
      }
    }
  }
}

__device__ __forceinline__ float dot8(uint4 a, uint4 b){
  return bflo(a.x)*bflo(b.x) + bfhi(a.x)*bfhi(b.x)
       + bflo(a.y)*bflo(b.y) + bfhi(a.y)*bfhi(b.y)
       + bflo(a.z)*bflo(b.z) + bfhi(a.z)*bfhi(b.z)
       + bflo(a.w)*bflo(b.w) + bfhi(a.w)*bfhi(b.w);
}

// ---------- single-pass edge attention: one wave per dst node, no atomics ----------
// qkv row layout: [0..1023] = q (key*128+h*16+dh), [1024..1535] = k (et*128+..), [1536..2047] = v
__global__ __launch_bounds__(256) void edge_attn(
    const u16* __restrict__ qkv, const int* __restrict__ key_ids,
    const int* __restrict__ rs, const int* __restrict__ deg,
    const u32* __restrict__ epk, u16* __restrict__ aggbf)
{
  int n = blockIdx.x * 4 + (threadIdx.x >> 6);
  int l = threadIdx.x & 63;
  int h = l & 7, s = l >> 3;               // head, edge-slot
  const u16* qp = qkv + (size_t)n * 2048 + (key_ids[n] << 7) + (h << 4);
  uint4 q0 = *(const uint4*)qp, q1 = *(const uint4*)(qp + 8);
  int e0 = rs[n], cnt = deg[n];
  float z = 0.f;
  float acc[16];
  #pragma unroll
  for (int j = 0; j < 16; j++) acc[j] = 0.f;
  for (int base = 0; base < cnt; base += 8){
    int idx = base + s;
    if (idx < cnt){
      u32 pk = epk[e0 + idx];
      int sn = pk >> 2, et = pk & 3;
      const u16* kp = qkv + (size_t)sn * 2048 + 1024 + (et << 7) + (h << 4);
      uint4 k0 = *(const uint4*)kp, k1 = *(const uint4*)(kp + 8);
      float sc = (dot8(q0, k0) + dot8(q1, k1)) * 0.25f;
      float ew = __expf(fminf(sc, 80.f));
      const u16* vp = kp + 512;
      uint4 v0 = *(const uint4*)vp, v1 = *(const uint4*)(vp + 8);
      z += ew;
      acc[0]  += ew * bflo(v0.x); acc[1]  += ew * bfhi(v0.x);
      acc[2]  += ew * bflo(v0.y); acc[3]  += ew * bfhi(v0.y);
      acc[4]  += ew * bflo(v0.z); acc[5]  += ew * bfhi(v0.z);
      acc[6]  += ew * bflo(v0.w); acc[7]  += ew * bfhi(v0.w);
      acc[8]  += ew * bflo(v1.x); acc[9]  += ew * bfhi(v1.x);
      acc[10] += ew * bflo(v1.y); acc[11] += ew * bfhi(v1.y);
      acc[12] += ew * bflo(v1.z); acc[13] += ew * bfhi(v1.z);
      acc[14] += ew * bflo(v1.w); acc[15] += ew * bfhi(v1.w);
    }
  }
  // reduce across the 8 slots of each head (lane-xor 8/16/32)
  #pragma unroll
  for (int m = 8; m < 64; m <<= 1){
    z += __shfl_xor(z, m, 64);
    #pragma unroll
    for (int j = 0; j < 16; j++) acc[j] += __shfl_xor(acc[j], m, 64);
  }
  float inv = 1.f / (z + 1e-9f);
  int j0 = s * 2;
  u32 pack = (u32)f2bf(acc[j0] * inv) | ((u32)f2bf(acc[j0 + 1] * inv) << 16);
  *(u32*)(aggbf + (size_t)n * 128 + (h << 4) + j0) = pack;
}

// ---------- select own-key h, relu, layernorm, residual; emit f32 + bf16 feat ----------
__global__ __launch_bounds__(128) void ln_update(
    const u16* __restrict__ hall,   // [N,1024] bf16
    const int* __restrict__ key_ids, const float* __restrict__ gbf,
    float* __restrict__ feat, u16* __restrict__ featbf, int blk)
{
  __shared__ float red[4];
  int n = blockIdx.x, t = threadIdx.x;
  int key = key_ids[n];
  float acc = fmaxf(bf2f(hall[(size_t)n * 1024 + (key << 7) + t]), 0.f);
  float v1 = acc, v2 = acc * acc;
  #pragma unroll
  for (int o = 32; o > 0; o >>= 1){
    v1 += __shfl_down(v1, o, 64);
    v2 += __shfl_down(v2, o, 64);
  }
  if ((t & 63) == 0){ int w = t >> 6; red[w] = v1; red[2 + w] = v2; }
  __syncthreads();
  float mu  = (red[0] + red[1]) * (1.f / 128.f);
  float ex2 = (red[2] + red[3]) * (1.f / 128.f);
  float var = ex2 - mu * mu;
  float y = (acc - mu) * rsqrtf(var + 1e-5f) * gbf[(blk << 7) + t] + gbf[256 + (blk << 7) + t];
  float r = y + feat[(n << 7) + t];
  feat[(n << 7) + t] = r;
  featbf[(n << 7) + t] = f2bf(r);
}

// ---------- target readout ----------
__global__ __launch_bounds__(128) void readout(
    const float* __restrict__ feat, const float* __restrict__ twf,
    const int* __restrict__ key_ids, const int* __restrict__ tgt,
    float* __restrict__ outacc, void* dout, const int* __restrict__ flag, int blk)
{
  int t = threadIdx.x;
  int n = tgt[t];
  int key = key_ids[n];
  const float* fr = feat + (n << 7);
  const float* wr = twf + (size_t)((blk * 8 + key) << 7);
  float acc = 0.f;
  #pragma unroll
  for (int d = 0; d < 128; d++) acc = fmaf(fr[d], wr[d], acc);
  if (blk == 0){
    outacc[t] = 0.5f * acc;
  } else {
    float r = outacc[t] + 0.5f * acc;
    if (*flag) ((u16*)dout)[t] = f2bf(r);
    else       ((float*)dout)[t] = r;
  }
}

extern "C" void kernel_launch(void* const* d_in, const int* in_sizes, int n_in,
                              void* d_out, int out_size, void* d_ws, size_t ws_size,
                              hipStream_t stream)
{
  const void* emb = d_in[0];
  const void* qw  = d_in[1];
  const void* kw  = d_in[2];
  const void* vw  = d_in[3];
  const void* nw  = d_in[4];
  const void* tw  = d_in[5];
  const void* lg  = d_in[6];
  const void* lb  = d_in[7];
  const int* value_ids = (const int*)d_in[8];
  const int* key_ids   = (const int*)d_in[9];
  const int* srcp  = (const int*)d_in[10];
  const int* dstp  = (const int*)d_in[11];
  const int* etp   = (const int*)d_in[12];
  const int* tgt   = (const int*)d_in[13];

  char* p = (char*)d_ws;
  auto carve = [&](size_t bytes)->char*{
    char* r = p; p += (bytes + 255) & ~(size_t)255; return r;
  };
  const int MPAD = 50048;  // 391*128
  int*   flag   = (int*)  carve(4);
  float* feat   = (float*)carve((size_t)N_NODES * 128 * 4);
  u16*   featbf = (u16*)  carve((size_t)N_NODES * 128 * 2);
  u16*   wcat   = (u16*)  carve((size_t)2 * 2048 * 128 * 2);  // per blk: [q 1024 | k 512 | v 512] x 128
  u16*   nwcat  = (u16*)  carve((size_t)2 * 1024 * 128 * 2);
  float* twf    = (float*)carve((size_t)2 * 8 * 128 * 4);
  float* gbf    = (float*)carve((size_t)512 * 4);
  int*   deg    = (int*)  carve((size_t)N_NODES * 4);
  int*   rs     = (int*)  carve((size_t)N_NODES * 4);
  int*   cur    = (int*)  carve((size_t)N_NODES * 4);
  u32*   epk    = (u32*)  carve((size_t)N_EDGES * 4);
  u16*   qkv    = (u16*)  carve((size_t)MPAD * 2048 * 2);     // aliased as h_all [MPAD,1024] after edge_attn
  u16*   aggbf  = (u16*)  carve((size_t)N_NODES * 128 * 2);
  float* outacc = (float*)carve((size_t)N_TARGETS * 4);
  u16*   hall   = qkv;   // alias: qkv dead once edge_attn finished
  (void)ws_size; (void)n_in; (void)in_sizes; (void)out_size;

  detect_dtype<<<1, 256, 0, stream>>>((const u16*)emb, flag);

  auto cbf = [&](const void* s, size_t so, u16* d, int n){
    cvt_bf<<<(n + 255) / 256, 256, 0, stream>>>(s, so, d, n, flag);
  };
  for (int b = 0; b < 2; b++){
    cbf(qw, (size_t)b * 1024 * 128, wcat + (size_t)b * 2048 * 128,              1024 * 128);
    cbf(kw, (size_t)b * 512  * 128, wcat + (size_t)b * 2048 * 128 + 1024 * 128, 512 * 128);
    cbf(vw, (size_t)b * 512  * 128, wcat + (size_t)b * 2048 * 128 + 1536 * 128, 512 * 128);
    cbf(nw, (size_t)b * 1024 * 128, nwcat + (size_t)b * 1024 * 128,             1024 * 128);
  }
  cvt_f32<<<(2048 + 255) / 256, 256, 0, stream>>>(tw, twf, 2048, flag);
  cvt_f32<<<1, 256, 0, stream>>>(lg, gbf, 256, flag);
  cvt_f32<<<1, 256, 0, stream>>>(lb, gbf + 256, 256, flag);

  gather_feat<<<(N_NODES * 128) / 256, 256, 0, stream>>>(emb, value_ids, flag, feat, featbf);

  hipMemsetAsync(deg, 0, (size_t)N_NODES * 4, stream);
  const int eg = (N_EDGES + 255) / 256;
  hist_dst<<<eg, 256, 0, stream>>>(dstp, deg);
  scan_deg<<<1, 1024, 0, stream>>>(deg, rs, cur);
  scatter_edges<<<eg, 256, 0, stream>>>(srcp, dstp, etp, cur, epk);

  for (int b = 0; b < NUM_BLOCKS; b++){
    gemm_bt<<<dim3(391, 16), 256, 0, stream>>>(featbf, wcat + (size_t)b * 2048 * 128,
                                               qkv, N_NODES, 2048);
    edge_attn<<<N_NODES / 4, 256, 0, stream>>>(qkv, key_ids, rs, deg, epk, aggbf);
    gemm_bt<<<dim3(391, 8), 256, 0, stream>>>(aggbf, nwcat + (size_t)b * 1024 * 128,
                                              hall, N_NODES, 1024);
    ln_update<<<N_NODES, 128, 0, stream>>>(hall, key_ids, gbf, feat, featbf, b);
    readout<<<1, 128, 0, stream>>>(feat, twf, key_ids, tgt, outacc, d_out, flag, b);
  }
}